// Round 6
// baseline (174.492 us; speedup 1.0000x reference)
//
#include <hip/hip_runtime.h>
#include <math.h>

// Problem constants
#define BATCH 256
#define IC    1152   // 32*6*6 input capsule positions
#define DD    8
#define OO    10
#define EE    16
#define BTILE 128    // batches per block (2 per thread)
#define NBT   2      // BATCH / BTILE
#define NT    640    // 10 waves, wave = one o
#define CHUNK 9      // ijk positions per block
#define NCHUNK 128   // IC / CHUNK -> grid 256 blocks, 1/CU
#define XP    (BTILE + 1)   // pad: staging writes (same b, 8 d's) hit distinct banks

// pass kernel: recompute u_hat from LDS-staged tiles.
//  R2-R5 lesson: wave-uniform scalar-W (SGPR) path is structurally ~35us --
//  SGPRs can't hold a 128-float W row, forcing serialized s_load->wait->FMA
//  chains. Instead: stage the WHOLE chunk's W (46 KB) + x (37 KB) in LDS once
//  per block, then the ijk loop is pure VALU + LDS dual-pipe:
//    per ijk/thread: 8 uniform ds_read_b128 (W) + 16 ds_read_b32 (x) + 256 FMA.
//  Barriers: 1 staging barrier; 1 per ijk for logit exchange (double-buffered;
//  ZERO loop barriers when first=1). No min-waves cap (R3: caps => spills).
__global__ __launch_bounds__(NT) void caps_pass_kernel(
    const float* __restrict__ x,       // [256][1152][8]
    const float* __restrict__ W,       // [1152][10][8][16]
    const float* __restrict__ V,       // [256][10][16] accumulated v
    float* __restrict__ s_part,        // [NCHUNK][256][10][16]
    int first)
{
    __shared__ __align__(16) float w_lds[CHUNK * OO * DD * EE];  // 11520 f = 46 KB
    __shared__ float x_lds[CHUNK][DD][XP];                       // 37 KB, d-major
    __shared__ float logit_lds[2][2][OO][64];                    // 10 KB

    const int tid = threadIdx.x;
    const int o   = tid >> 6;        // wave id 0..9
    const int bl  = tid & 63;
    const int o_u = __builtin_amdgcn_readfirstlane(o);
    const int b0  = blockIdx.y * BTILE + bl;
    const int b1  = b0 + 64;
    const int ijk0 = blockIdx.x * CHUNK;

    // ---- stage W: contiguous 2880 float4, fully coalesced ----
    {
        const float4* wg = reinterpret_cast<const float4*>(W + (size_t)ijk0 * (OO * DD * EE));
        float4* wl = reinterpret_cast<float4*>(w_lds);
        #pragma unroll
        for (int i = 0; i < 5; ++i) {
            int idx = tid + i * NT;
            if (idx < (CHUNK * OO * DD * EE) / 4) wl[idx] = wg[idx];
        }
    }
    // ---- stage x: 2304 float4 -> padded d-major layout ----
    for (int idx = tid; idx < CHUNK * BTILE * 2; idx += NT) {
        int b_l = idx / (CHUNK * 2);          // 18 consecutive idx per b: 288B runs
        int rem = idx - b_l * (CHUNK * 2);
        int ij  = rem >> 1;
        int q   = rem & 1;
        float4 t = *reinterpret_cast<const float4*>(
            x + (size_t)(blockIdx.y * BTILE + b_l) * (IC * DD)
              + (size_t)(ijk0 + ij) * DD + q * 4);
        x_lds[ij][q * 4 + 0][b_l] = t.x;
        x_lds[ij][q * 4 + 1][b_l] = t.y;
        x_lds[ij][q * 4 + 2][b_l] = t.z;
        x_lds[ij][q * 4 + 3][b_l] = t.w;
    }

    // per-thread V[b,o,:] for both batches
    float v0[EE], v1[EE];
    if (first) {
        #pragma unroll
        for (int e = 0; e < EE; ++e) { v0[e] = 0.f; v1[e] = 0.f; }
    } else {
        const float4* vp0 = reinterpret_cast<const float4*>(V + ((size_t)b0 * OO + o) * EE);
        const float4* vp1 = reinterpret_cast<const float4*>(V + ((size_t)b1 * OO + o) * EE);
        #pragma unroll
        for (int q = 0; q < 4; ++q) {
            float4 t0 = vp0[q], t1 = vp1[q];
            v0[q*4+0]=t0.x; v0[q*4+1]=t0.y; v0[q*4+2]=t0.z; v0[q*4+3]=t0.w;
            v1[q*4+0]=t1.x; v1[q*4+1]=t1.y; v1[q*4+2]=t1.z; v1[q*4+3]=t1.w;
        }
    }

    float s0[EE], s1[EE];
    #pragma unroll
    for (int e = 0; e < EE; ++e) { s0[e] = 0.f; s1[e] = 0.f; }

    __syncthreads();   // staging complete

    for (int r = 0; r < CHUNK; ++r) {
        // u for both batches; W broadcast from LDS (uniform addr), x per-lane
        const float4* wrow = reinterpret_cast<const float4*>(
            &w_lds[(size_t)(r * OO + o_u) * (DD * EE)]);
        float u0[EE], u1[EE];
        #pragma unroll
        for (int e = 0; e < EE; ++e) { u0[e] = 0.f; u1[e] = 0.f; }
        #pragma unroll
        for (int d = 0; d < DD; ++d) {
            float x0 = x_lds[r][d][bl];
            float x1 = x_lds[r][d][bl + 64];
            #pragma unroll
            for (int q = 0; q < 4; ++q) {
                float4 w4 = wrow[d * 4 + q];
                u0[q*4+0] = fmaf(x0, w4.x, u0[q*4+0]);
                u0[q*4+1] = fmaf(x0, w4.y, u0[q*4+1]);
                u0[q*4+2] = fmaf(x0, w4.z, u0[q*4+2]);
                u0[q*4+3] = fmaf(x0, w4.w, u0[q*4+3]);
                u1[q*4+0] = fmaf(x1, w4.x, u1[q*4+0]);
                u1[q*4+1] = fmaf(x1, w4.y, u1[q*4+1]);
                u1[q*4+2] = fmaf(x1, w4.z, u1[q*4+2]);
                u1[q*4+3] = fmaf(x1, w4.w, u1[q*4+3]);
            }
        }

        float c0, c1;
        if (first) {
            c0 = 0.1f; c1 = 0.1f;      // softmax of zero logits over O=10
        } else {
            float lg0 = 0.f, lg1 = 0.f;
            #pragma unroll
            for (int e = 0; e < EE; ++e) {
                lg0 = fmaf(u0[e], v0[e], lg0);
                lg1 = fmaf(u1[e], v1[e], lg1);
            }
            const int pb = r & 1;      // double-buffered: 1 barrier per ijk
            logit_lds[pb][0][o][bl] = lg0;
            logit_lds[pb][1][o][bl] = lg1;
            __syncthreads();
            // max-free softmax: |logit| = |u.v| <~ 1, exp safe
            float d0 = 0.f, d1 = 0.f;
            #pragma unroll
            for (int oo = 0; oo < OO; ++oo) {
                d0 += __expf(logit_lds[pb][0][oo][bl]);
                d1 += __expf(logit_lds[pb][1][oo][bl]);
            }
            c0 = __expf(lg0) / d0;
            c1 = __expf(lg1) / d1;
        }

        #pragma unroll
        for (int e = 0; e < EE; ++e) {
            s0[e] = fmaf(c0, u0[e], s0[e]);
            s1[e] = fmaf(c1, u1[e], s1[e]);
        }
    }

    // write partial s for this chunk, both batch halves
    float* sp0 = s_part + (((size_t)blockIdx.x * BATCH + b0) * OO + o) * EE;
    float* sp1 = s_part + (((size_t)blockIdx.x * BATCH + b1) * OO + o) * EE;
    #pragma unroll
    for (int q = 0; q < 4; ++q) {
        float4 t0, t1;
        t0.x = s0[q*4+0]; t0.y = s0[q*4+1]; t0.z = s0[q*4+2]; t0.w = s0[q*4+3];
        t1.x = s1[q*4+0]; t1.y = s1[q*4+1]; t1.z = s1[q*4+2]; t1.w = s1[q*4+3];
        reinterpret_cast<float4*>(sp0)[q] = t0;
        reinterpret_cast<float4*>(sp1)[q] = t1;
    }
}

// squash kernel: reduce partial s over chunks, squash, update V (or write out).
__global__ __launch_bounds__(256) void caps_squash_kernel(
    const float* __restrict__ s_part,  // [NCHUNK][256][10][16]
    float* __restrict__ V,             // [256][10][16]
    float* __restrict__ out,           // [256][10][16]
    int accum, int last)
{
    const int g = blockIdx.x * 256 + threadIdx.x;   // < 40960
    float s = 0.f;
    #pragma unroll 8
    for (int ch = 0; ch < NCHUNK; ++ch)
        s += s_part[(size_t)ch * (BATCH * OO * EE) + g];

    // squared norm over the 16-element e axis (lanes g..g+15 share (b,o))
    float sq = s * s;
    #pragma unroll
    for (int m = 1; m < 16; m <<= 1) sq += __shfl_xor(sq, m, 16);

    float scale = sq / (1.f + sq) / (sqrtf(sq) + 1e-6f);
    float v = scale * s;

    if (last)       out[g] = v;
    else if (accum) V[g]  += v;
    else            V[g]   = v;
}

extern "C" void kernel_launch(void* const* d_in, const int* in_sizes, int n_in,
                              void* d_out, int out_size, void* d_ws, size_t ws_size,
                              hipStream_t stream) {
    const float* x = (const float*)d_in[0];   // [256,32,6,6,8]
    const float* W = (const float*)d_in[1];   // [1,32,6,6,10,8,16]
    float* out = (float*)d_out;               // [256,10,16]

    float* s_part = (float*)d_ws;                                   // NCHUNK*40960 floats
    float* V      = s_part + (size_t)NCHUNK * BATCH * OO * EE;      // 40960 floats

    dim3 grid(NCHUNK, NBT), blk(NT);
    const int sq_blocks = (BATCH * OO * EE) / 256;   // 160

    // iteration 1: b=0 -> c uniform 0.1; v1 -> V
    caps_pass_kernel<<<grid, blk, 0, stream>>>(x, W, V, s_part, 1);
    caps_squash_kernel<<<sq_blocks, 256, 0, stream>>>(s_part, V, out, 0, 0);
    // iteration 2: logits = dot(u_hat, v1); V += v2
    caps_pass_kernel<<<grid, blk, 0, stream>>>(x, W, V, s_part, 0);
    caps_squash_kernel<<<sq_blocks, 256, 0, stream>>>(s_part, V, out, 1, 0);
    // iteration 3 (final): logits = dot(u_hat, v1+v2); output v3
    caps_pass_kernel<<<grid, blk, 0, stream>>>(x, W, V, s_part, 0);
    caps_squash_kernel<<<sq_blocks, 256, 0, stream>>>(s_part, V, out, 0, 1);
}

// Round 7
// 167.705 us; speedup vs baseline: 1.0405x; 1.0405x over previous
//
#include <hip/hip_runtime.h>
#include <math.h>

// Problem constants
#define BATCH 256
#define IC    1152   // 32*6*6 input capsule positions
#define DD    8
#define OO    10
#define EE    16
#define BTILE 128    // batches per block (2 per thread)
#define NBT   2      // BATCH / BTILE
#define NT    640    // 10 waves, wave = one o
#define CHUNK 9      // ijk positions per block
#define NCHUNK 128   // IC / CHUNK -> grid 256 blocks, 1/CU
#define XP    (BTILE + 1)   // pad: staging writes (same b, 8 d's) hit distinct banks

// pass kernel: recompute u_hat from LDS-staged tiles.
//  R2-R6 lesson: pass time (~35-38us) is invariant to the data path (SGPR-W,
//  LDS-W, ILP) while VALU/LDS models both predict ~7-18us -> the shared
//  bottleneck is the FULLY-UNROLLED ijk loop (~25-100KB straight-line code,
//  I$ is 32KB/2CU) => instruction-fetch streaming, VALUBusy pinned ~22%.
//  Fix: #pragma unroll 1 on the ijk loop; body (~1 ijk) stays I$-resident.
//  Also: store exp(logit) in LDS (saves 20 v_exp per thread-ijk).
__global__ __launch_bounds__(NT) void caps_pass_kernel(
    const float* __restrict__ x,       // [256][1152][8]
    const float* __restrict__ W,       // [1152][10][8][16]
    const float* __restrict__ V,       // [256][10][16] accumulated v
    float* __restrict__ s_part,        // [NCHUNK][256][10][16]
    int first)
{
    __shared__ __align__(16) float w_lds[CHUNK * OO * DD * EE];  // 11520 f = 46 KB
    __shared__ float x_lds[CHUNK][DD][XP];                       // 37 KB, d-major
    __shared__ float elogit_lds[2][2][OO][64];                   // 10 KB (exp of logits)

    const int tid = threadIdx.x;
    const int o   = tid >> 6;        // wave id 0..9
    const int bl  = tid & 63;
    const int o_u = __builtin_amdgcn_readfirstlane(o);
    const int b0  = blockIdx.y * BTILE + bl;
    const int b1  = b0 + 64;
    const int ijk0 = blockIdx.x * CHUNK;

    // ---- stage W: contiguous 2880 float4, fully coalesced ----
    {
        const float4* wg = reinterpret_cast<const float4*>(W + (size_t)ijk0 * (OO * DD * EE));
        float4* wl = reinterpret_cast<float4*>(w_lds);
        #pragma unroll
        for (int i = 0; i < 5; ++i) {
            int idx = tid + i * NT;
            if (idx < (CHUNK * OO * DD * EE) / 4) wl[idx] = wg[idx];
        }
    }
    // ---- stage x: 2304 float4 -> padded d-major layout ----
    #pragma unroll 1
    for (int idx = tid; idx < CHUNK * BTILE * 2; idx += NT) {
        int b_l = idx / (CHUNK * 2);          // 18 consecutive idx per b: 288B runs
        int rem = idx - b_l * (CHUNK * 2);
        int ij  = rem >> 1;
        int q   = rem & 1;
        float4 t = *reinterpret_cast<const float4*>(
            x + (size_t)(blockIdx.y * BTILE + b_l) * (IC * DD)
              + (size_t)(ijk0 + ij) * DD + q * 4);
        x_lds[ij][q * 4 + 0][b_l] = t.x;
        x_lds[ij][q * 4 + 1][b_l] = t.y;
        x_lds[ij][q * 4 + 2][b_l] = t.z;
        x_lds[ij][q * 4 + 3][b_l] = t.w;
    }

    // per-thread V[b,o,:] for both batches
    float v0[EE], v1[EE];
    if (first) {
        #pragma unroll
        for (int e = 0; e < EE; ++e) { v0[e] = 0.f; v1[e] = 0.f; }
    } else {
        const float4* vp0 = reinterpret_cast<const float4*>(V + ((size_t)b0 * OO + o) * EE);
        const float4* vp1 = reinterpret_cast<const float4*>(V + ((size_t)b1 * OO + o) * EE);
        #pragma unroll
        for (int q = 0; q < 4; ++q) {
            float4 t0 = vp0[q], t1 = vp1[q];
            v0[q*4+0]=t0.x; v0[q*4+1]=t0.y; v0[q*4+2]=t0.z; v0[q*4+3]=t0.w;
            v1[q*4+0]=t1.x; v1[q*4+1]=t1.y; v1[q*4+2]=t1.z; v1[q*4+3]=t1.w;
        }
    }

    float s0[EE], s1[EE];
    #pragma unroll
    for (int e = 0; e < EE; ++e) { s0[e] = 0.f; s1[e] = 0.f; }

    __syncthreads();   // staging complete

    #pragma unroll 1   // CRITICAL: keep body I$-resident (see header comment)
    for (int r = 0; r < CHUNK; ++r) {
        // u for both batches; W broadcast from LDS (uniform addr), x per-lane
        const float4* wrow = reinterpret_cast<const float4*>(
            &w_lds[(size_t)(r * OO + o_u) * (DD * EE)]);
        float u0[EE], u1[EE];
        #pragma unroll
        for (int e = 0; e < EE; ++e) { u0[e] = 0.f; u1[e] = 0.f; }
        #pragma unroll
        for (int d = 0; d < DD; ++d) {
            float x0 = x_lds[r][d][bl];
            float x1 = x_lds[r][d][bl + 64];
            #pragma unroll
            for (int q = 0; q < 4; ++q) {
                float4 w4 = wrow[d * 4 + q];
                u0[q*4+0] = fmaf(x0, w4.x, u0[q*4+0]);
                u0[q*4+1] = fmaf(x0, w4.y, u0[q*4+1]);
                u0[q*4+2] = fmaf(x0, w4.z, u0[q*4+2]);
                u0[q*4+3] = fmaf(x0, w4.w, u0[q*4+3]);
                u1[q*4+0] = fmaf(x1, w4.x, u1[q*4+0]);
                u1[q*4+1] = fmaf(x1, w4.y, u1[q*4+1]);
                u1[q*4+2] = fmaf(x1, w4.z, u1[q*4+2]);
                u1[q*4+3] = fmaf(x1, w4.w, u1[q*4+3]);
            }
        }

        float c0, c1;
        if (first) {
            c0 = 0.1f; c1 = 0.1f;      // softmax of zero logits over O=10
        } else {
            float lg0 = 0.f, lg1 = 0.f;
            #pragma unroll
            for (int e = 0; e < EE; ++e) {
                lg0 = fmaf(u0[e], v0[e], lg0);
                lg1 = fmaf(u1[e], v1[e], lg1);
            }
            // max-free softmax (|logit| = |u.v| <~ 1); store exp directly
            float e0 = __expf(lg0), e1 = __expf(lg1);
            const int pb = r & 1;      // double-buffered: 1 barrier per ijk
            elogit_lds[pb][0][o][bl] = e0;
            elogit_lds[pb][1][o][bl] = e1;
            __syncthreads();
            float d0 = 0.f, d1 = 0.f;
            #pragma unroll
            for (int oo = 0; oo < OO; ++oo) {
                d0 += elogit_lds[pb][0][oo][bl];
                d1 += elogit_lds[pb][1][oo][bl];
            }
            c0 = e0 / d0;
            c1 = e1 / d1;
        }

        #pragma unroll
        for (int e = 0; e < EE; ++e) {
            s0[e] = fmaf(c0, u0[e], s0[e]);
            s1[e] = fmaf(c1, u1[e], s1[e]);
        }
    }

    // write partial s for this chunk, both batch halves
    float* sp0 = s_part + (((size_t)blockIdx.x * BATCH + b0) * OO + o) * EE;
    float* sp1 = s_part + (((size_t)blockIdx.x * BATCH + b1) * OO + o) * EE;
    #pragma unroll
    for (int q = 0; q < 4; ++q) {
        float4 t0, t1;
        t0.x = s0[q*4+0]; t0.y = s0[q*4+1]; t0.z = s0[q*4+2]; t0.w = s0[q*4+3];
        t1.x = s1[q*4+0]; t1.y = s1[q*4+1]; t1.z = s1[q*4+2]; t1.w = s1[q*4+3];
        reinterpret_cast<float4*>(sp0)[q] = t0;
        reinterpret_cast<float4*>(sp1)[q] = t1;
    }
}

// squash kernel: reduce partial s over chunks, squash, update V (or write out).
__global__ __launch_bounds__(256) void caps_squash_kernel(
    const float* __restrict__ s_part,  // [NCHUNK][256][10][16]
    float* __restrict__ V,             // [256][10][16]
    float* __restrict__ out,           // [256][10][16]
    int accum, int last)
{
    const int g = blockIdx.x * 256 + threadIdx.x;   // < 40960
    float s = 0.f;
    #pragma unroll 8
    for (int ch = 0; ch < NCHUNK; ++ch)
        s += s_part[(size_t)ch * (BATCH * OO * EE) + g];

    // squared norm over the 16-element e axis (lanes g..g+15 share (b,o))
    float sq = s * s;
    #pragma unroll
    for (int m = 1; m < 16; m <<= 1) sq += __shfl_xor(sq, m, 16);

    float scale = sq / (1.f + sq) / (sqrtf(sq) + 1e-6f);
    float v = scale * s;

    if (last)       out[g] = v;
    else if (accum) V[g]  += v;
    else            V[g]   = v;
}

extern "C" void kernel_launch(void* const* d_in, const int* in_sizes, int n_in,
                              void* d_out, int out_size, void* d_ws, size_t ws_size,
                              hipStream_t stream) {
    const float* x = (const float*)d_in[0];   // [256,32,6,6,8]
    const float* W = (const float*)d_in[1];   // [1,32,6,6,10,8,16]
    float* out = (float*)d_out;               // [256,10,16]

    float* s_part = (float*)d_ws;                                   // NCHUNK*40960 floats
    float* V      = s_part + (size_t)NCHUNK * BATCH * OO * EE;      // 40960 floats

    dim3 grid(NCHUNK, NBT), blk(NT);
    const int sq_blocks = (BATCH * OO * EE) / 256;   // 160

    // iteration 1: b=0 -> c uniform 0.1; v1 -> V
    caps_pass_kernel<<<grid, blk, 0, stream>>>(x, W, V, s_part, 1);
    caps_squash_kernel<<<sq_blocks, 256, 0, stream>>>(s_part, V, out, 0, 0);
    // iteration 2: logits = dot(u_hat, v1); V += v2
    caps_pass_kernel<<<grid, blk, 0, stream>>>(x, W, V, s_part, 0);
    caps_squash_kernel<<<sq_blocks, 256, 0, stream>>>(s_part, V, out, 1, 0);
    // iteration 3 (final): logits = dot(u_hat, v1+v2); output v3
    caps_pass_kernel<<<grid, blk, 0, stream>>>(x, W, V, s_part, 0);
    caps_squash_kernel<<<sq_blocks, 256, 0, stream>>>(s_part, V, out, 0, 1);
}